// Round 7
// baseline (241.254 us; speedup 1.0000x reference)
//
#include <hip/hip_runtime.h>
#include <hip/hip_bf16.h>
#include <math.h>

using bf16 = __hip_bfloat16;
typedef __bf16 bf16x8v __attribute__((ext_vector_type(8)));
typedef float f32x4v __attribute__((ext_vector_type(4)));

#define AS1 __attribute__((address_space(1)))
#define AS3 __attribute__((address_space(3)))

// async global->LDS, 16B/lane; LDS dest = wave-uniform base + lane*16
__device__ __forceinline__ void g2l16(const void* g, void* l) {
  __builtin_amdgcn_global_load_lds((const AS1 void*)g, (AS3 void*)l, 16, 0, 0);
}

__device__ __forceinline__ float fclamp(float v) {
  return fminf(fmaxf(v, -6.0e4f), 6.0e4f);  // NaN firewall
}

// pack two floats to adjacent bf16 (compiler emits v_cvt_pk_bf16_f32)
__device__ __forceinline__ unsigned packbf(float a, float b) {
  unsigned short lo = __builtin_bit_cast(unsigned short, __float2bfloat16(a));
  unsigned short hi = __builtin_bit_cast(unsigned short, __float2bfloat16(b));
  return (unsigned)lo | ((unsigned)hi << 16);
}

// scale*log2(e), folded into Q projection so attn uses plain exp2
#define QSCL 0.1803368801111204f

// ---------------------------------------------------------------------------
// Fused transpose + fp32->bf16 for all 4 weights.
// ---------------------------------------------------------------------------
__global__ __launch_bounds__(256) void transpose_cvt4(
    const float* __restrict__ w0, const float* __restrict__ w1,
    const float* __restrict__ w2, const float* __restrict__ w3,
    bf16* __restrict__ o0, bf16* __restrict__ o1,
    bf16* __restrict__ o2, bf16* __restrict__ o3) {
  const float* in = (blockIdx.z == 0) ? w0 : (blockIdx.z == 1) ? w1
                    : (blockIdx.z == 2) ? w2 : w3;
  bf16* out = (blockIdx.z == 0) ? o0 : (blockIdx.z == 1) ? o1
              : (blockIdx.z == 2) ? o2 : o3;
  __shared__ alignas(16) bf16 tile[64][80];
  const int t = threadIdx.x;
  const int bx = blockIdx.x * 64, by = blockIdx.y * 64;
#pragma unroll
  for (int p = 0; p < 4; ++p) {
    int idx = p * 1024 + t * 4;
    int r = idx >> 6, c0 = idx & 63;
    float4 v = *(const float4*)&in[(size_t)(by + r) * 1024 + bx + c0];
    tile[c0 + 0][r] = __float2bfloat16(v.x);
    tile[c0 + 1][r] = __float2bfloat16(v.y);
    tile[c0 + 2][r] = __float2bfloat16(v.z);
    tile[c0 + 3][r] = __float2bfloat16(v.w);
  }
  __syncthreads();
#pragma unroll
  for (int p = 0; p < 2; ++p) {
    int idx = p * 2048 + t * 8;
    int c = idx >> 6, r0 = idx & 63;
    *(uint4*)&out[(size_t)(bx + c) * 1024 + by + r0] = *(const uint4*)&tile[c][r0];
  }
}

// ---------------------------------------------------------------------------
// Fused QKV GEMM: A fp32 read directly (cvt3 kernel eliminated).
//  - A: raw float4 loads issued EARLY (before compute), cvt+ds_write into
//    the other buffer AFTER compute (T14 split) -> HBM latency hides under
//    the 16 MFMA of the current K-step.
//  - B: g2l16 prefetch one K-step ahead.
//  - Single __syncthreads() per K-step (drains vmcnt + makes writes visible),
//    vs the old 2-barrier loop that exposed staging latency 32 times.
// z: 0=Q (QSCL folded), 1=K (head-split), 2=V (split+transpose, 8B stores).
// ---------------------------------------------------------------------------
__global__ __launch_bounds__(256, 2) void gemm_qkv(
    const float* __restrict__ Aq, const float* __restrict__ Ak,
    const float* __restrict__ Av,
    const bf16* __restrict__ WtQ, const bf16* __restrict__ WtK,
    const bf16* __restrict__ WtV,
    const float* __restrict__ bq, const float* __restrict__ bk_,
    const float* __restrict__ bv_,
    bf16* __restrict__ Qh, bf16* __restrict__ Kh, bf16* __restrict__ Vt) {
  constexpr int K = 1024, LDA = 40;
  const int z = blockIdx.z;
  const float* A  = (z == 0) ? Aq : (z == 1) ? Ak : Av;
  const bf16* Bt  = (z == 0) ? WtQ : (z == 1) ? WtK : WtV;
  const float* bias = (z == 0) ? bq : (z == 1) ? bk_ : bv_;
  bf16* C = (z == 0) ? Qh : (z == 1) ? Kh : Vt;

  __shared__ alignas(16) bf16 As[2][128 * LDA];  // reg-staged (padded)
  __shared__ alignas(16) bf16 Bs[2][128 * 32];   // g2l16 (linear)
  const int t = threadIdx.x;
  const int wave = t >> 6, lane = t & 63;
  const int quad = lane >> 4, l16 = lane & 15;
  const int bm = blockIdx.x * 128, bn = blockIdx.y * 128;
  const int wm = (wave & 1) * 64, wn = (wave >> 1) * 64;

  f32x4v acc[4][4] = {};

  auto loadA = [&](int k0, float4* f) {
#pragma unroll
    for (int c = 0; c < 2; ++c) {
      int idx = c * 2048 + t * 8;
      int row = idx >> 5, col = idx & 31;
      const float* src = &A[(size_t)(bm + row) * K + k0 + col];
      f[c * 2 + 0] = *(const float4*)src;
      f[c * 2 + 1] = *(const float4*)(src + 4);
    }
  };
  auto writeA = [&](int buf, const float4* f) {
#pragma unroll
    for (int c = 0; c < 2; ++c) {
      int idx = c * 2048 + t * 8;
      int row = idx >> 5, col = idx & 31;
      uint4 u;
      u.x = packbf(f[c * 2 + 0].x, f[c * 2 + 0].y);
      u.y = packbf(f[c * 2 + 0].z, f[c * 2 + 0].w);
      u.z = packbf(f[c * 2 + 1].x, f[c * 2 + 1].y);
      u.w = packbf(f[c * 2 + 1].z, f[c * 2 + 1].w);
      *(uint4*)&As[buf][row * LDA + col] = u;
    }
  };
  auto stageB = [&](int k0, int buf) {
#pragma unroll
    for (int c = 0; c < 2; ++c) {
      int idx = c * 2048 + t * 8;
      int row = idx >> 5, col = idx & 31;
      g2l16(&Bt[(size_t)(bn + row) * K + k0 + col],
            &Bs[buf][c * 2048 + wave * 512]);
    }
  };

  // prologue: stage K-step 0 into buf 0
  {
    float4 f0[4];
    loadA(0, f0);
    stageB(0, 0);
    writeA(0, f0);
    __syncthreads();  // vmcnt(0): B staged; lgkm: A writes visible
  }

  int buf = 0;
  for (int k0 = 0; k0 < K; k0 += 32) {
    const bool more = (k0 + 32) < K;
    float4 fN[4];
    if (more) {
      loadA(k0 + 32, fN);      // issue early; consumed after compute
      stageB(k0 + 32, buf ^ 1);
    }

    bf16x8v a[4], b[4];
#pragma unroll
    for (int mi = 0; mi < 4; ++mi)
      a[mi] = *(const bf16x8v*)&As[buf][(wm + mi * 16 + l16) * LDA + quad * 8];
#pragma unroll
    for (int ni = 0; ni < 4; ++ni)
      b[ni] = *(const bf16x8v*)&Bs[buf][(wn + ni * 16 + l16) * 32 + quad * 8];
#pragma unroll
    for (int mi = 0; mi < 4; ++mi)
#pragma unroll
      for (int ni = 0; ni < 4; ++ni)
        acc[mi][ni] = __builtin_amdgcn_mfma_f32_16x16x32_bf16(a[mi], b[ni],
                                                              acc[mi][ni], 0, 0, 0);

    if (more) writeA(buf ^ 1, fN);  // cvt+write after compute (loads drained)
    __syncthreads();  // one barrier/K-step: drains B g2l16 + A ds_writes
    buf ^= 1;
  }

  if (z == 2) {
    // V^T store: s = m&2047 contiguous along r -> pack 4 bf16 per 8B store
#pragma unroll
    for (int ni = 0; ni < 4; ++ni) {
      int n = bn + wn + ni * 16 + l16;
      float bz = bias[n];
      int h_ = n >> 6, d_ = n & 63;
#pragma unroll
      for (int mi = 0; mi < 4; ++mi) {
        int m0 = bm + wm + mi * 16 + quad * 4;
        int b_ = m0 >> 11, s0 = m0 & 2047;
        uint2 u;
        u.x = packbf(fclamp(acc[mi][ni][0] + bz), fclamp(acc[mi][ni][1] + bz));
        u.y = packbf(fclamp(acc[mi][ni][2] + bz), fclamp(acc[mi][ni][3] + bz));
        *(uint2*)&C[((size_t)(b_ * 16 + h_) * 64 + d_) * 2048 + s0] = u;
      }
    }
  } else {
    const float scl = (z == 0) ? QSCL : 1.0f;  // fold softmax scale into Q
#pragma unroll
    for (int ni = 0; ni < 4; ++ni) {
      int n = bn + wn + ni * 16 + l16;
      float bz = bias[n];
      int h_ = n >> 6, d_ = n & 63;
#pragma unroll
      for (int mi = 0; mi < 4; ++mi)
#pragma unroll
        for (int r = 0; r < 4; ++r) {
          int m = bm + wm + mi * 16 + quad * 4 + r;
          int b_ = m >> 11, s_ = m & 2047;
          C[((size_t)(b_ * 16 + h_) * 2048 + s_) * 64 + d_] =
              __float2bfloat16(fclamp(acc[mi][ni][r] + bz) * scl);
        }
    }
  }
}

// ---------------------------------------------------------------------------
// Output projection: 128x64 tile, single-barrier double-buffered pipeline.
// ---------------------------------------------------------------------------
__global__ __launch_bounds__(256, 2) void gemm_out(
    const bf16* __restrict__ A, const bf16* __restrict__ Bt,
    const float* __restrict__ bias, float* __restrict__ C) {
  constexpr int K = 1024, N = 1024;
  __shared__ alignas(16) bf16 As[2][128 * 32];
  __shared__ alignas(16) bf16 Bs[2][64 * 32];
  const int t = threadIdx.x;
  const int wave = t >> 6, lane = t & 63;
  const int quad = lane >> 4, l16 = lane & 15;
  const int bm = blockIdx.x * 128, bn = blockIdx.y * 64;
  const int wm = (wave & 1) * 64, wn = (wave >> 1) * 32;

  f32x4v acc[4][2] = {};

  auto stage = [&](int k0, int buf) {
#pragma unroll
    for (int c = 0; c < 2; ++c) {
      int idx = c * 2048 + t * 8;
      int row = idx >> 5, col = idx & 31;
      g2l16(&A[(size_t)(bm + row) * K + k0 + col],
            &As[buf][c * 2048 + wave * 512]);
    }
    {
      int idx = t * 8;
      int row = idx >> 5, col = idx & 31;
      g2l16(&Bt[(size_t)(bn + row) * K + k0 + col], &Bs[buf][wave * 512]);
    }
  };

  stage(0, 0);
  __syncthreads();

  int buf = 0;
  for (int k0 = 0; k0 < K; k0 += 32) {
    if (k0 + 32 < K) stage(k0 + 32, buf ^ 1);

    bf16x8v a[4], b[2];
#pragma unroll
    for (int mi = 0; mi < 4; ++mi)
      a[mi] = *(const bf16x8v*)&As[buf][(wm + mi * 16 + l16) * 32 + quad * 8];
#pragma unroll
    for (int ni = 0; ni < 2; ++ni)
      b[ni] = *(const bf16x8v*)&Bs[buf][(wn + ni * 16 + l16) * 32 + quad * 8];
#pragma unroll
    for (int mi = 0; mi < 4; ++mi)
#pragma unroll
      for (int ni = 0; ni < 2; ++ni)
        acc[mi][ni] = __builtin_amdgcn_mfma_f32_16x16x32_bf16(a[mi], b[ni],
                                                              acc[mi][ni], 0, 0, 0);
    __syncthreads();  // drains next-step g2l16; all reads of buf done
    buf ^= 1;
  }

#pragma unroll
  for (int ni = 0; ni < 2; ++ni) {
    int n = bn + wn + ni * 16 + l16;
    float bz = bias[n];
#pragma unroll
    for (int mi = 0; mi < 4; ++mi)
#pragma unroll
      for (int r = 0; r < 4; ++r) {
        int m = bm + wm + mi * 16 + quad * 4 + r;
        C[(size_t)m * N + n] = fclamp(acc[mi][ni][r] + bz);
      }
  }
}

// ---------------------------------------------------------------------------
// Flash attention v8 (best measured: 59.7 us): 512-thread blocks (8 waves,
// 16 q-rows/wave), XCD-bijective decode (FETCH 12 MB), triple-buffered
// 2-ahead prefetch with counted vmcnt(2), swapped QK^T + packed b64 P-store,
// Qs/Ps union, Q-hoist, MFMA row-sum, setprio, XOR chunk swizzle.
// ---------------------------------------------------------------------------
__global__ __launch_bounds__(512, 4) void attn(
    const bf16* __restrict__ Qh, const bf16* __restrict__ Kh,
    const bf16* __restrict__ Vt, bf16* __restrict__ Ctx) {
  constexpr int LDPP = 40;  // Ps row stride (16B-aligned rows: 80 B)
  __shared__ alignas(16) bf16 QsPs[128 * 64];  // Qs (prologue) / Ps (main loop)
  __shared__ alignas(16) bf16 Ks[3][64 * 64];
  __shared__ alignas(16) bf16 Vs[3][64 * 64];
  const int t = threadIdx.x;
  const int wave = t >> 6, lane = t & 63;  // wave 0..7
  const int quad = lane >> 4, l16 = lane & 15;
  const int sw = l16 & 7;  // per-lane chunk swizzle key (row&7 == l16&7)

  // XCD-bijective decode: lin%8 = XCD; each XCD gets 4 bh x 16 qb.
  const int lin = blockIdx.x;       // 0..511
  const int li = lin >> 3;          // 0..63
  const int qb = li & 15;           // 0..15
  const int bh = (lin & 7) * 4 + (li >> 4);  // 0..31

  const size_t bh_off = (size_t)bh * 2048 * 64;
  const bf16* Qb = Qh + bh_off;
  const bf16* Kb = Kh + bh_off;
  const bf16* Vb = Vt + bh_off;  // [64][2048]

  // staging coords: 512 threads cover one 64x64 tile in a single pass
  const int srow = t >> 3;   // 0..63
  const int schunk = t & 7;

  auto stageKV = [&](int kt, int buf) {
    int mc = schunk ^ (srow & 7);
    g2l16(&Kb[(size_t)(kt * 64 + srow) * 64 + mc * 8], &Ks[buf][wave * 512]);
    g2l16(&Vb[(size_t)srow * 2048 + kt * 64 + mc * 8], &Vs[buf][wave * 512]);
  };

  // prologue: Q (2 loads) then tile 0 (2 loads); vmcnt(2) -> Q done.
#pragma unroll
  for (int c = 0; c < 2; ++c) {
    int row = c * 64 + srow;
    int mc = schunk ^ (row & 7);
    g2l16(&Qb[(size_t)(qb * 128 + row) * 64 + mc * 8],
          &QsPs[c * 4096 + wave * 512]);
  }
  stageKV(0, 0);
  asm volatile("s_waitcnt vmcnt(2)" ::: "memory");
  __builtin_amdgcn_s_barrier();

  // Q-hoist: fragments are kt-invariant, keep in registers (8 VGPR)
  bf16x8v aq[2];  // [kk]
#pragma unroll
  for (int kk = 0; kk < 2; ++kk)
    aq[kk] = *(const bf16x8v*)
        &QsPs[(wave * 16 + l16) * 64 + (((kk * 4 + quad) ^ sw) << 3)];

  // Qs region now dead -> reuse as Ps. __syncthreads drains vmcnt too.
  __syncthreads();
  bf16* Psw = QsPs + wave * (16 * LDPP);  // per-wave P buffer (1280 B)

  stageKV(1, 1);  // prefetch depth builds: tile 1 in flight

  // all-ones B fragment for MFMA row-sum
  bf16x8v vone;
#pragma unroll
  for (int i = 0; i < 8; ++i) vone[i] = (__bf16)1.0f;

  f32x4v lsum = {};
  f32x4v oacc[4] = {};

  auto compute = [&](int buf) {
#pragma unroll
    for (int h = 0; h < 2; ++h) {  // 32-key halves
      // S^T = K(32x64) x Q^T(64x16): row=key(quad*4+r), col=q(l16)
      f32x4v s[2] = {};  // [ni]
      __builtin_amdgcn_s_setprio(1);
#pragma unroll
      for (int kk = 0; kk < 2; ++kk)
#pragma unroll
        for (int ni = 0; ni < 2; ++ni) {
          bf16x8v bk = *(const bf16x8v*)
              &Ks[buf][(h * 32 + ni * 16 + l16) * 64 + (((kk * 4 + quad) ^ sw) << 3)];
          s[ni] = __builtin_amdgcn_mfma_f32_16x16x32_bf16(bk, aq[kk],
                                                          s[ni], 0, 0, 0);
        }
      __builtin_amdgcn_s_setprio(0);

      // P = exp2(S); 4 consecutive keys/lane -> pack -> one b64 write each.
#pragma unroll
      for (int ni = 0; ni < 2; ++ni) {
        float p0 = __builtin_amdgcn_exp2f(fminf(s[ni][0], 80.f));
        float p1 = __builtin_amdgcn_exp2f(fminf(s[ni][1], 80.f));
        float p2 = __builtin_amdgcn_exp2f(fminf(s[ni][2], 80.f));
        float p3 = __builtin_amdgcn_exp2f(fminf(s[ni][3], 80.f));
        uint2 u;
        u.x = packbf(p0, p1);
        u.y = packbf(p2, p3);
        *(uint2*)&Psw[l16 * LDPP + ni * 16 + quad * 4] = u;
      }

      // O += P(16x32) x V(32x64); l += P x ones (row-sum on matrix pipe)
      bf16x8v ap = *(const bf16x8v*)&Psw[l16 * LDPP + quad * 8];
      __builtin_amdgcn_s_setprio(1);
      lsum = __builtin_amdgcn_mfma_f32_16x16x32_bf16(ap, vone, lsum, 0, 0, 0);
#pragma unroll
      for (int ni = 0; ni < 4; ++ni) {
        bf16x8v bv = *(const bf16x8v*)
            &Vs[buf][(ni * 16 + l16) * 64 + (((h * 4 + quad) ^ sw) << 3)];
        oacc[ni] = __builtin_amdgcn_mfma_f32_16x16x32_bf16(ap, bv, oacc[ni],
                                                           0, 0, 0);
      }
      __builtin_amdgcn_s_setprio(0);
    }
  };

  // main loop, 2-ahead: stage(t+2) -> compute(t) -> vmcnt(2) -> barrier.
  int bufc = 0;
  for (int tt = 0; tt < 30; ++tt) {
    int bufs = bufc + 2; if (bufs >= 3) bufs -= 3;
    stageKV(tt + 2, bufs);
    compute(bufc);
    asm volatile("s_waitcnt vmcnt(2)" ::: "memory");
    __builtin_amdgcn_s_barrier();
    bufc = (bufc == 2) ? 0 : bufc + 1;
  }
  compute(bufc);
  asm volatile("s_waitcnt vmcnt(0)" ::: "memory");
  __builtin_amdgcn_s_barrier();
  bufc = (bufc == 2) ? 0 : bufc + 1;
  compute(bufc);

  // epilogue: O / l -> Ctx[b][s][h*64+dh]
  const int b_ = bh >> 4, h_ = bh & 15;
#pragma unroll
  for (int r = 0; r < 4; ++r) {
    int sr = qb * 128 + wave * 16 + quad * 4 + r;
    float inv = 1.0f / fmaxf(lsum[r], 1.0e-20f);
#pragma unroll
    for (int ni = 0; ni < 4; ++ni) {
      int col = h_ * 64 + ni * 16 + l16;
      Ctx[(size_t)(b_ * 2048 + sr) * 1024 + col] =
          __float2bfloat16(fclamp(oacc[ni][r] * inv));
    }
  }
}

extern "C" void kernel_launch(void* const* d_in, const int* in_sizes, int n_in,
                              void* d_out, int out_size, void* d_ws, size_t ws_size,
                              hipStream_t stream) {
  const float* q   = (const float*)d_in[0];
  const float* k   = (const float*)d_in[1];
  const float* v   = (const float*)d_in[2];
  const float* w_q = (const float*)d_in[3];
  const float* b_q = (const float*)d_in[4];
  const float* w_k = (const float*)d_in[5];
  const float* b_k = (const float*)d_in[6];
  const float* w_v = (const float*)d_in[7];
  const float* b_v = (const float*)d_in[8];
  const float* w_o = (const float*)d_in[9];
  const float* b_o = (const float*)d_in[10];
  float* out = (float*)d_out;

  char* ws = (char*)d_ws;
  const size_t MB = (size_t)1024 * 1024;
  bf16* WtQ = (bf16*)(ws + 0 * MB);
  bf16* WtK = (bf16*)(ws + 2 * MB);
  bf16* WtV = (bf16*)(ws + 4 * MB);
  bf16* WtO = (bf16*)(ws + 6 * MB);
  bf16* Qh  = (bf16*)(ws + 8 * MB);   // [2,16,2048,64]
  bf16* Kh  = (bf16*)(ws + 16 * MB);
  bf16* Vt  = (bf16*)(ws + 24 * MB);  // [2,16,64,2048]
  bf16* Ctx = (bf16*)(ws + 32 * MB);  // [2,2048,1024]

  dim3 tb(256);
  transpose_cvt4<<<dim3(16, 16, 4), tb, 0, stream>>>(w_q, w_k, w_v, w_o,
                                                     WtQ, WtK, WtV, WtO);
  gemm_qkv<<<dim3(32, 8, 3), tb, 0, stream>>>(q, k, v, WtQ, WtK, WtV,
                                              b_q, b_k, b_v, Qh, Kh, Vt);
  attn<<<dim3(512), dim3(512), 0, stream>>>(Qh, Kh, Vt, Ctx);
  gemm_out<<<dim3(32, 16), tb, 0, stream>>>(Ctx, WtO, b_o, out);
}

// Round 8
// 224.568 us; speedup vs baseline: 1.0743x; 1.0743x over previous
//
#include <hip/hip_runtime.h>
#include <hip/hip_bf16.h>
#include <math.h>

using bf16 = __hip_bfloat16;
typedef __bf16 bf16x8v __attribute__((ext_vector_type(8)));
typedef float f32x4v __attribute__((ext_vector_type(4)));

#define AS1 __attribute__((address_space(1)))
#define AS3 __attribute__((address_space(3)))

// async global->LDS, 16B/lane; LDS dest = wave-uniform base + lane*16
__device__ __forceinline__ void g2l16(const void* g, void* l) {
  __builtin_amdgcn_global_load_lds((const AS1 void*)g, (AS3 void*)l, 16, 0, 0);
}

__device__ __forceinline__ float fclamp(float v) {
  return fminf(fmaxf(v, -6.0e4f), 6.0e4f);  // NaN firewall
}

// pack two floats to adjacent bf16 (compiler emits v_cvt_pk_bf16_f32)
__device__ __forceinline__ unsigned packbf(float a, float b) {
  unsigned short lo = __builtin_bit_cast(unsigned short, __float2bfloat16(a));
  unsigned short hi = __builtin_bit_cast(unsigned short, __float2bfloat16(b));
  return (unsigned)lo | ((unsigned)hi << 16);
}

// scale*log2(e), folded into Q projection so attn uses plain exp2
#define QSCL 0.1803368801111204f

// ---------------------------------------------------------------------------
// Fused transpose + fp32->bf16 for all 4 weights.
// ---------------------------------------------------------------------------
__global__ __launch_bounds__(256) void transpose_cvt4(
    const float* __restrict__ w0, const float* __restrict__ w1,
    const float* __restrict__ w2, const float* __restrict__ w3,
    bf16* __restrict__ o0, bf16* __restrict__ o1,
    bf16* __restrict__ o2, bf16* __restrict__ o3) {
  const float* in = (blockIdx.z == 0) ? w0 : (blockIdx.z == 1) ? w1
                    : (blockIdx.z == 2) ? w2 : w3;
  bf16* out = (blockIdx.z == 0) ? o0 : (blockIdx.z == 1) ? o1
              : (blockIdx.z == 2) ? o2 : o3;
  __shared__ alignas(16) bf16 tile[64][80];
  const int t = threadIdx.x;
  const int bx = blockIdx.x * 64, by = blockIdx.y * 64;
#pragma unroll
  for (int p = 0; p < 4; ++p) {
    int idx = p * 1024 + t * 4;
    int r = idx >> 6, c0 = idx & 63;
    float4 v = *(const float4*)&in[(size_t)(by + r) * 1024 + bx + c0];
    tile[c0 + 0][r] = __float2bfloat16(v.x);
    tile[c0 + 1][r] = __float2bfloat16(v.y);
    tile[c0 + 2][r] = __float2bfloat16(v.z);
    tile[c0 + 3][r] = __float2bfloat16(v.w);
  }
  __syncthreads();
#pragma unroll
  for (int p = 0; p < 2; ++p) {
    int idx = p * 2048 + t * 8;
    int c = idx >> 6, r0 = idx & 63;
    *(uint4*)&out[(size_t)(bx + c) * 1024 + by + r0] = *(const uint4*)&tile[c][r0];
  }
}

// ---------------------------------------------------------------------------
// fp32 -> bf16 for q,k,v (blockIdx.y selects tensor), 8 elems/thread.
// One-shot convert: amortizes the fp32->bf16 cost once instead of per
// bn-block inside the GEMM (R7 fusion regressed: 2x load bytes + VALU).
// ---------------------------------------------------------------------------
__global__ __launch_bounds__(256) void cvt3(
    const float* __restrict__ q, const float* __restrict__ k,
    const float* __restrict__ v, bf16* __restrict__ oq,
    bf16* __restrict__ ok, bf16* __restrict__ ov) {
  const float* in = (blockIdx.y == 0) ? q : (blockIdx.y == 1) ? k : v;
  bf16* out = (blockIdx.y == 0) ? oq : (blockIdx.y == 1) ? ok : ov;
  int i = (blockIdx.x * 256 + threadIdx.x) * 8;
  float4 a = *(const float4*)&in[i];
  float4 b = *(const float4*)&in[i + 4];
  uint4 u;
  u.x = packbf(a.x, a.y); u.y = packbf(a.z, a.w);
  u.z = packbf(b.x, b.y); u.w = packbf(b.z, b.w);
  *(uint4*)&out[i] = u;
}

// ---------------------------------------------------------------------------
// QKV GEMM: A bf16 [4096x1024], Bt = W^T [N][K] bf16.
// Triple-buffered 2-ahead pipeline (attn-v8 scheme ported): stage(t+2) via
// g2l16 -> compute(t) -> counted vmcnt(4) [stage t+1 complete, t+2 still in
// flight] -> one barrier per K-step. Replaces the 2-barrier m97 loop that
// exposed full staging latency 32x. LDS 48 KB -> 2 blocks/CU.
// z: 0=Q (QSCL folded), 1=K (head-split), 2=V (split+transpose, 8B stores).
// ---------------------------------------------------------------------------
__global__ __launch_bounds__(256, 2) void gemm_qkv_bf16(
    const bf16* __restrict__ Aq, const bf16* __restrict__ Ak,
    const bf16* __restrict__ Av,
    const bf16* __restrict__ WtQ, const bf16* __restrict__ WtK,
    const bf16* __restrict__ WtV,
    const float* __restrict__ bq, const float* __restrict__ bk_,
    const float* __restrict__ bv_,
    bf16* __restrict__ Qh, bf16* __restrict__ Kh, bf16* __restrict__ Vt) {
  constexpr int K = 1024;
  const int z = blockIdx.z;
  const bf16* A    = (z == 0) ? Aq : (z == 1) ? Ak : Av;
  const bf16* Bt   = (z == 0) ? WtQ : (z == 1) ? WtK : WtV;
  const float* bias = (z == 0) ? bq : (z == 1) ? bk_ : bv_;
  bf16* C = (z == 0) ? Qh : (z == 1) ? Kh : Vt;

  __shared__ alignas(16) bf16 As[3][128 * 32];
  __shared__ alignas(16) bf16 Bs[3][128 * 32];
  const int t = threadIdx.x;
  const int wave = t >> 6, lane = t & 63;
  const int quad = lane >> 4, l16 = lane & 15;
  const int bm = blockIdx.x * 128, bn = blockIdx.y * 128;
  const int wm = (wave & 1) * 64, wn = (wave >> 1) * 64;

  f32x4v acc[4][4] = {};

  auto stage = [&](int ks, int buf) {  // ks = K-step 0..31 (4 g2l16/thread)
    int k0 = ks * 32;
#pragma unroll
    for (int c = 0; c < 2; ++c) {
      int idx = c * 2048 + t * 8;
      int row = idx >> 5, col = idx & 31;
      g2l16(&A[(size_t)(bm + row) * K + k0 + col], &As[buf][c * 2048 + wave * 512]);
      g2l16(&Bt[(size_t)(bn + row) * K + k0 + col], &Bs[buf][c * 2048 + wave * 512]);
    }
  };

  auto compute = [&](int buf) {
    bf16x8v a[4], b[4];
#pragma unroll
    for (int mi = 0; mi < 4; ++mi)
      a[mi] = *(const bf16x8v*)&As[buf][(wm + mi * 16 + l16) * 32 + quad * 8];
#pragma unroll
    for (int ni = 0; ni < 4; ++ni)
      b[ni] = *(const bf16x8v*)&Bs[buf][(wn + ni * 16 + l16) * 32 + quad * 8];
#pragma unroll
    for (int mi = 0; mi < 4; ++mi)
#pragma unroll
      for (int ni = 0; ni < 4; ++ni)
        acc[mi][ni] = __builtin_amdgcn_mfma_f32_16x16x32_bf16(a[mi], b[ni],
                                                              acc[mi][ni], 0, 0, 0);
  };

  // prologue: tile 0 resident, tile 1 in flight
  stage(0, 0);
  asm volatile("s_waitcnt vmcnt(0)" ::: "memory");
  __builtin_amdgcn_s_barrier();
  stage(1, 1);

  int bufc = 0;
  for (int tt = 0; tt < 30; ++tt) {
    int bufs = bufc + 2; if (bufs >= 3) bufs -= 3;
    stage(tt + 2, bufs);   // buffer (tt+2)%3: readers done at barrier tt-1
    compute(bufc);
    asm volatile("s_waitcnt vmcnt(4)" ::: "memory");  // t+1 done, t+2 in flight
    __builtin_amdgcn_s_barrier();
    bufc = (bufc == 2) ? 0 : bufc + 1;
  }
  compute(bufc);
  asm volatile("s_waitcnt vmcnt(0)" ::: "memory");
  __builtin_amdgcn_s_barrier();
  bufc = (bufc == 2) ? 0 : bufc + 1;
  compute(bufc);

  if (z == 2) {
    // V^T store: s = m&2047 contiguous along r -> pack 4 bf16 per 8B store
#pragma unroll
    for (int ni = 0; ni < 4; ++ni) {
      int n = bn + wn + ni * 16 + l16;
      float bz = bias[n];
      int h_ = n >> 6, d_ = n & 63;
#pragma unroll
      for (int mi = 0; mi < 4; ++mi) {
        int m0 = bm + wm + mi * 16 + quad * 4;
        int b_ = m0 >> 11, s0 = m0 & 2047;
        uint2 u;
        u.x = packbf(fclamp(acc[mi][ni][0] + bz), fclamp(acc[mi][ni][1] + bz));
        u.y = packbf(fclamp(acc[mi][ni][2] + bz), fclamp(acc[mi][ni][3] + bz));
        *(uint2*)&C[((size_t)(b_ * 16 + h_) * 64 + d_) * 2048 + s0] = u;
      }
    }
  } else {
    const float scl = (z == 0) ? QSCL : 1.0f;  // fold softmax scale into Q
#pragma unroll
    for (int ni = 0; ni < 4; ++ni) {
      int n = bn + wn + ni * 16 + l16;
      float bz = bias[n];
      int h_ = n >> 6, d_ = n & 63;
#pragma unroll
      for (int mi = 0; mi < 4; ++mi)
#pragma unroll
        for (int r = 0; r < 4; ++r) {
          int m = bm + wm + mi * 16 + quad * 4 + r;
          int b_ = m >> 11, s_ = m & 2047;
          C[((size_t)(b_ * 16 + h_) * 2048 + s_) * 64 + d_] =
              __float2bfloat16(fclamp(acc[mi][ni][r] + bz) * scl);
        }
    }
  }
}

// ---------------------------------------------------------------------------
// Output projection: 128x64 tile, same triple-buffered 2-ahead pipeline
// (3 g2l16/stage -> vmcnt(3)). LDS 36 KB -> 2 blocks/CU.
// ---------------------------------------------------------------------------
__global__ __launch_bounds__(256, 2) void gemm_out(
    const bf16* __restrict__ A, const bf16* __restrict__ Bt,
    const float* __restrict__ bias, float* __restrict__ C) {
  constexpr int K = 1024, N = 1024;
  __shared__ alignas(16) bf16 As[3][128 * 32];
  __shared__ alignas(16) bf16 Bs[3][64 * 32];
  const int t = threadIdx.x;
  const int wave = t >> 6, lane = t & 63;
  const int quad = lane >> 4, l16 = lane & 15;
  const int bm = blockIdx.x * 128, bn = blockIdx.y * 64;
  const int wm = (wave & 1) * 64, wn = (wave >> 1) * 32;

  f32x4v acc[4][2] = {};

  auto stage = [&](int ks, int buf) {  // 3 g2l16/thread
    int k0 = ks * 32;
#pragma unroll
    for (int c = 0; c < 2; ++c) {
      int idx = c * 2048 + t * 8;
      int row = idx >> 5, col = idx & 31;
      g2l16(&A[(size_t)(bm + row) * K + k0 + col], &As[buf][c * 2048 + wave * 512]);
    }
    {
      int idx = t * 8;
      int row = idx >> 5, col = idx & 31;
      g2l16(&Bt[(size_t)(bn + row) * K + k0 + col], &Bs[buf][wave * 512]);
    }
  };

  auto compute = [&](int buf) {
    bf16x8v a[4], b[2];
#pragma unroll
    for (int mi = 0; mi < 4; ++mi)
      a[mi] = *(const bf16x8v*)&As[buf][(wm + mi * 16 + l16) * 32 + quad * 8];
#pragma unroll
    for (int ni = 0; ni < 2; ++ni)
      b[ni] = *(const bf16x8v*)&Bs[buf][(wn + ni * 16 + l16) * 32 + quad * 8];
#pragma unroll
    for (int mi = 0; mi < 4; ++mi)
#pragma unroll
      for (int ni = 0; ni < 2; ++ni)
        acc[mi][ni] = __builtin_amdgcn_mfma_f32_16x16x32_bf16(a[mi], b[ni],
                                                              acc[mi][ni], 0, 0, 0);
  };

  stage(0, 0);
  asm volatile("s_waitcnt vmcnt(0)" ::: "memory");
  __builtin_amdgcn_s_barrier();
  stage(1, 1);

  int bufc = 0;
  for (int tt = 0; tt < 30; ++tt) {
    int bufs = bufc + 2; if (bufs >= 3) bufs -= 3;
    stage(tt + 2, bufs);
    compute(bufc);
    asm volatile("s_waitcnt vmcnt(3)" ::: "memory");
    __builtin_amdgcn_s_barrier();
    bufc = (bufc == 2) ? 0 : bufc + 1;
  }
  compute(bufc);
  asm volatile("s_waitcnt vmcnt(0)" ::: "memory");
  __builtin_amdgcn_s_barrier();
  bufc = (bufc == 2) ? 0 : bufc + 1;
  compute(bufc);

#pragma unroll
  for (int ni = 0; ni < 2; ++ni) {
    int n = bn + wn + ni * 16 + l16;
    float bz = bias[n];
#pragma unroll
    for (int mi = 0; mi < 4; ++mi)
#pragma unroll
      for (int r = 0; r < 4; ++r) {
        int m = bm + wm + mi * 16 + quad * 4 + r;
        C[(size_t)m * N + n] = fclamp(acc[mi][ni][r] + bz);
      }
  }
}

// ---------------------------------------------------------------------------
// Flash attention v8 (best measured: 59.7 us): 512-thread blocks (8 waves,
// 16 q-rows/wave), XCD-bijective decode (FETCH 12 MB), triple-buffered
// 2-ahead prefetch with counted vmcnt(2), swapped QK^T + packed b64 P-store,
// Qs/Ps union, Q-hoist, MFMA row-sum, setprio, XOR chunk swizzle.
// ---------------------------------------------------------------------------
__global__ __launch_bounds__(512, 4) void attn(
    const bf16* __restrict__ Qh, const bf16* __restrict__ Kh,
    const bf16* __restrict__ Vt, bf16* __restrict__ Ctx) {
  constexpr int LDPP = 40;  // Ps row stride (16B-aligned rows: 80 B)
  __shared__ alignas(16) bf16 QsPs[128 * 64];  // Qs (prologue) / Ps (main loop)
  __shared__ alignas(16) bf16 Ks[3][64 * 64];
  __shared__ alignas(16) bf16 Vs[3][64 * 64];
  const int t = threadIdx.x;
  const int wave = t >> 6, lane = t & 63;  // wave 0..7
  const int quad = lane >> 4, l16 = lane & 15;
  const int sw = l16 & 7;  // per-lane chunk swizzle key (row&7 == l16&7)

  // XCD-bijective decode: lin%8 = XCD; each XCD gets 4 bh x 16 qb.
  const int lin = blockIdx.x;       // 0..511
  const int li = lin >> 3;          // 0..63
  const int qb = li & 15;           // 0..15
  const int bh = (lin & 7) * 4 + (li >> 4);  // 0..31

  const size_t bh_off = (size_t)bh * 2048 * 64;
  const bf16* Qb = Qh + bh_off;
  const bf16* Kb = Kh + bh_off;
  const bf16* Vb = Vt + bh_off;  // [64][2048]

  // staging coords: 512 threads cover one 64x64 tile in a single pass
  const int srow = t >> 3;   // 0..63
  const int schunk = t & 7;

  auto stageKV = [&](int kt, int buf) {
    int mc = schunk ^ (srow & 7);
    g2l16(&Kb[(size_t)(kt * 64 + srow) * 64 + mc * 8], &Ks[buf][wave * 512]);
    g2l16(&Vb[(size_t)srow * 2048 + kt * 64 + mc * 8], &Vs[buf][wave * 512]);
  };

  // prologue: Q (2 loads) then tile 0 (2 loads); vmcnt(2) -> Q done.
#pragma unroll
  for (int c = 0; c < 2; ++c) {
    int row = c * 64 + srow;
    int mc = schunk ^ (row & 7);
    g2l16(&Qb[(size_t)(qb * 128 + row) * 64 + mc * 8],
          &QsPs[c * 4096 + wave * 512]);
  }
  stageKV(0, 0);
  asm volatile("s_waitcnt vmcnt(2)" ::: "memory");
  __builtin_amdgcn_s_barrier();

  // Q-hoist: fragments are kt-invariant, keep in registers (8 VGPR)
  bf16x8v aq[2];  // [kk]
#pragma unroll
  for (int kk = 0; kk < 2; ++kk)
    aq[kk] = *(const bf16x8v*)
        &QsPs[(wave * 16 + l16) * 64 + (((kk * 4 + quad) ^ sw) << 3)];

  // Qs region now dead -> reuse as Ps. __syncthreads drains vmcnt too.
  __syncthreads();
  bf16* Psw = QsPs + wave * (16 * LDPP);  // per-wave P buffer (1280 B)

  stageKV(1, 1);  // prefetch depth builds: tile 1 in flight

  // all-ones B fragment for MFMA row-sum
  bf16x8v vone;
#pragma unroll
  for (int i = 0; i < 8; ++i) vone[i] = (__bf16)1.0f;

  f32x4v lsum = {};
  f32x4v oacc[4] = {};

  auto compute = [&](int buf) {
#pragma unroll
    for (int h = 0; h < 2; ++h) {  // 32-key halves
      // S^T = K(32x64) x Q^T(64x16): row=key(quad*4+r), col=q(l16)
      f32x4v s[2] = {};  // [ni]
      __builtin_amdgcn_s_setprio(1);
#pragma unroll
      for (int kk = 0; kk < 2; ++kk)
#pragma unroll
        for (int ni = 0; ni < 2; ++ni) {
          bf16x8v bk = *(const bf16x8v*)
              &Ks[buf][(h * 32 + ni * 16 + l16) * 64 + (((kk * 4 + quad) ^ sw) << 3)];
          s[ni] = __builtin_amdgcn_mfma_f32_16x16x32_bf16(bk, aq[kk],
                                                          s[ni], 0, 0, 0);
        }
      __builtin_amdgcn_s_setprio(0);

      // P = exp2(S); 4 consecutive keys/lane -> pack -> one b64 write each.
#pragma unroll
      for (int ni = 0; ni < 2; ++ni) {
        float p0 = __builtin_amdgcn_exp2f(fminf(s[ni][0], 80.f));
        float p1 = __builtin_amdgcn_exp2f(fminf(s[ni][1], 80.f));
        float p2 = __builtin_amdgcn_exp2f(fminf(s[ni][2], 80.f));
        float p3 = __builtin_amdgcn_exp2f(fminf(s[ni][3], 80.f));
        uint2 u;
        u.x = packbf(p0, p1);
        u.y = packbf(p2, p3);
        *(uint2*)&Psw[l16 * LDPP + ni * 16 + quad * 4] = u;
      }

      // O += P(16x32) x V(32x64); l += P x ones (row-sum on matrix pipe)
      bf16x8v ap = *(const bf16x8v*)&Psw[l16 * LDPP + quad * 8];
      __builtin_amdgcn_s_setprio(1);
      lsum = __builtin_amdgcn_mfma_f32_16x16x32_bf16(ap, vone, lsum, 0, 0, 0);
#pragma unroll
      for (int ni = 0; ni < 4; ++ni) {
        bf16x8v bv = *(const bf16x8v*)
            &Vs[buf][(ni * 16 + l16) * 64 + (((h * 4 + quad) ^ sw) << 3)];
        oacc[ni] = __builtin_amdgcn_mfma_f32_16x16x32_bf16(ap, bv, oacc[ni],
                                                           0, 0, 0);
      }
      __builtin_amdgcn_s_setprio(0);
    }
  };

  // main loop, 2-ahead: stage(t+2) -> compute(t) -> vmcnt(2) -> barrier.
  int bufc = 0;
  for (int tt = 0; tt < 30; ++tt) {
    int bufs = bufc + 2; if (bufs >= 3) bufs -= 3;
    stageKV(tt + 2, bufs);
    compute(bufc);
    asm volatile("s_waitcnt vmcnt(2)" ::: "memory");
    __builtin_amdgcn_s_barrier();
    bufc = (bufc == 2) ? 0 : bufc + 1;
  }
  compute(bufc);
  asm volatile("s_waitcnt vmcnt(0)" ::: "memory");
  __builtin_amdgcn_s_barrier();
  bufc = (bufc == 2) ? 0 : bufc + 1;
  compute(bufc);

  // epilogue: O / l -> Ctx[b][s][h*64+dh]
  const int b_ = bh >> 4, h_ = bh & 15;
#pragma unroll
  for (int r = 0; r < 4; ++r) {
    int sr = qb * 128 + wave * 16 + quad * 4 + r;
    float inv = 1.0f / fmaxf(lsum[r], 1.0e-20f);
#pragma unroll
    for (int ni = 0; ni < 4; ++ni) {
      int col = h_ * 64 + ni * 16 + l16;
      Ctx[(size_t)(b_ * 2048 + sr) * 1024 + col] =
          __float2bfloat16(fclamp(oacc[ni][r] * inv));
    }
  }
}

extern "C" void kernel_launch(void* const* d_in, const int* in_sizes, int n_in,
                              void* d_out, int out_size, void* d_ws, size_t ws_size,
                              hipStream_t stream) {
  const float* q   = (const float*)d_in[0];
  const float* k   = (const float*)d_in[1];
  const float* v   = (const float*)d_in[2];
  const float* w_q = (const float*)d_in[3];
  const float* b_q = (const float*)d_in[4];
  const float* w_k = (const float*)d_in[5];
  const float* b_k = (const float*)d_in[6];
  const float* w_v = (const float*)d_in[7];
  const float* b_v = (const float*)d_in[8];
  const float* w_o = (const float*)d_in[9];
  const float* b_o = (const float*)d_in[10];
  float* out = (float*)d_out;

  char* ws = (char*)d_ws;
  const size_t MB = (size_t)1024 * 1024;
  bf16* WtQ = (bf16*)(ws + 0 * MB);
  bf16* WtK = (bf16*)(ws + 2 * MB);
  bf16* WtV = (bf16*)(ws + 4 * MB);
  bf16* WtO = (bf16*)(ws + 6 * MB);
  bf16* Qa  = (bf16*)(ws + 8 * MB);   // bf16 activations (8 MiB each)
  bf16* Ka  = (bf16*)(ws + 16 * MB);
  bf16* Va  = (bf16*)(ws + 24 * MB);
  bf16* Qh  = (bf16*)(ws + 32 * MB);  // [2,16,2048,64]
  bf16* Kh  = (bf16*)(ws + 40 * MB);
  bf16* Vt  = (bf16*)(ws + 48 * MB);  // [2,16,64,2048]
  bf16* Ctx = Qa;                     // Qa dead after gemm_qkv

  dim3 tb(256);
  transpose_cvt4<<<dim3(16, 16, 4), tb, 0, stream>>>(w_q, w_k, w_v, w_o,
                                                     WtQ, WtK, WtV, WtO);
  cvt3<<<dim3(2048, 3), tb, 0, stream>>>(q, k, v, Qa, Ka, Va);
  gemm_qkv_bf16<<<dim3(32, 8, 3), tb, 0, stream>>>(Qa, Ka, Va, WtQ, WtK, WtV,
                                                   b_q, b_k, b_v, Qh, Kh, Vt);
  attn<<<dim3(512), dim3(512), 0, stream>>>(Qh, Kh, Vt, Ctx);
  gemm_out<<<dim3(32, 16), tb, 0, stream>>>(Ctx, WtO, b_o, out);
}

// Round 9
// 223.821 us; speedup vs baseline: 1.0779x; 1.0033x over previous
//
#include <hip/hip_runtime.h>
#include <hip/hip_bf16.h>
#include <math.h>

using bf16 = __hip_bfloat16;
typedef __bf16 bf16x8v __attribute__((ext_vector_type(8)));
typedef float f32x4v __attribute__((ext_vector_type(4)));

#define AS1 __attribute__((address_space(1)))
#define AS3 __attribute__((address_space(3)))

// async global->LDS, 16B/lane; LDS dest = wave-uniform base + lane*16
__device__ __forceinline__ void g2l16(const void* g, void* l) {
  __builtin_amdgcn_global_load_lds((const AS1 void*)g, (AS3 void*)l, 16, 0, 0);
}

__device__ __forceinline__ float fclamp(float v) {
  return fminf(fmaxf(v, -6.0e4f), 6.0e4f);  // NaN firewall
}

// pack two floats to adjacent bf16 (compiler emits v_cvt_pk_bf16_f32)
__device__ __forceinline__ unsigned packbf(float a, float b) {
  unsigned short lo = __builtin_bit_cast(unsigned short, __float2bfloat16(a));
  unsigned short hi = __builtin_bit_cast(unsigned short, __float2bfloat16(b));
  return (unsigned)lo | ((unsigned)hi << 16);
}

// scale*log2(e), folded into Q projection so attn uses plain exp2
#define QSCL 0.1803368801111204f

// ---------------------------------------------------------------------------
// Merged prep: activations fp32->bf16 (lin < 6144) + weight transpose+cvt
// (lin >= 6144). One launch instead of two (launch-overhead save).
// ---------------------------------------------------------------------------
__global__ __launch_bounds__(256) void prep(
    const float* __restrict__ q, const float* __restrict__ k,
    const float* __restrict__ v,
    const float* __restrict__ w0, const float* __restrict__ w1,
    const float* __restrict__ w2, const float* __restrict__ w3,
    bf16* __restrict__ oq, bf16* __restrict__ ok, bf16* __restrict__ ov,
    bf16* __restrict__ o0, bf16* __restrict__ o1,
    bf16* __restrict__ o2, bf16* __restrict__ o3) {
  __shared__ alignas(16) bf16 tile[64][80];
  const int t = threadIdx.x;
  const int lin = blockIdx.x;
  if (lin < 6144) {  // cvt path: 3 tensors x 2048 blocks
    const int tensor = lin >> 11, blk = lin & 2047;
    const float* in = (tensor == 0) ? q : (tensor == 1) ? k : v;
    bf16* out = (tensor == 0) ? oq : (tensor == 1) ? ok : ov;
    int i = (blk * 256 + t) * 8;
    float4 a = *(const float4*)&in[i];
    float4 b = *(const float4*)&in[i + 4];
    uint4 u;
    u.x = packbf(a.x, a.y); u.y = packbf(a.z, a.w);
    u.z = packbf(b.x, b.y); u.w = packbf(b.z, b.w);
    *(uint4*)&out[i] = u;
    return;
  }
  // transpose path: 4 weights x 256 tiles
  const int rem = lin - 6144;
  const int z = rem >> 8, xy = rem & 255;
  const float* in = (z == 0) ? w0 : (z == 1) ? w1 : (z == 2) ? w2 : w3;
  bf16* out = (z == 0) ? o0 : (z == 1) ? o1 : (z == 2) ? o2 : o3;
  const int bx = (xy & 15) * 64, by = (xy >> 4) * 64;
#pragma unroll
  for (int p = 0; p < 4; ++p) {
    int idx = p * 1024 + t * 4;
    int r = idx >> 6, c0 = idx & 63;
    float4 vv = *(const float4*)&in[(size_t)(by + r) * 1024 + bx + c0];
    tile[c0 + 0][r] = __float2bfloat16(vv.x);
    tile[c0 + 1][r] = __float2bfloat16(vv.y);
    tile[c0 + 2][r] = __float2bfloat16(vv.z);
    tile[c0 + 3][r] = __float2bfloat16(vv.w);
  }
  __syncthreads();
#pragma unroll
  for (int p = 0; p < 2; ++p) {
    int idx = p * 2048 + t * 8;
    int c = idx >> 6, r0 = idx & 63;
    *(uint4*)&out[(size_t)(bx + c) * 1024 + by + r0] = *(const uint4*)&tile[c][r0];
  }
}

// ---------------------------------------------------------------------------
// QKV GEMM: A bf16 [4096x1024], Bt = W^T [N][K] bf16.
// Triple-buffered 2-ahead pipeline, counted vmcnt(4). LDS 48 KB.
// z: 0=Q (QSCL folded), 1=K (head-split), 2=V (split+transpose, 8B stores).
// ---------------------------------------------------------------------------
__global__ __launch_bounds__(256, 2) void gemm_qkv_bf16(
    const bf16* __restrict__ Aq, const bf16* __restrict__ Ak,
    const bf16* __restrict__ Av,
    const bf16* __restrict__ WtQ, const bf16* __restrict__ WtK,
    const bf16* __restrict__ WtV,
    const float* __restrict__ bq, const float* __restrict__ bk_,
    const float* __restrict__ bv_,
    bf16* __restrict__ Qh, bf16* __restrict__ Kh, bf16* __restrict__ Vt) {
  constexpr int K = 1024;
  const int z = blockIdx.z;
  const bf16* A    = (z == 0) ? Aq : (z == 1) ? Ak : Av;
  const bf16* Bt   = (z == 0) ? WtQ : (z == 1) ? WtK : WtV;
  const float* bias = (z == 0) ? bq : (z == 1) ? bk_ : bv_;
  bf16* C = (z == 0) ? Qh : (z == 1) ? Kh : Vt;

  __shared__ alignas(16) bf16 As[3][128 * 32];
  __shared__ alignas(16) bf16 Bs[3][128 * 32];
  const int t = threadIdx.x;
  const int wave = t >> 6, lane = t & 63;
  const int quad = lane >> 4, l16 = lane & 15;
  const int bm = blockIdx.x * 128, bn = blockIdx.y * 128;
  const int wm = (wave & 1) * 64, wn = (wave >> 1) * 64;

  f32x4v acc[4][4] = {};

  auto stage = [&](int ks, int buf) {  // 4 g2l16/thread
    int k0 = ks * 32;
#pragma unroll
    for (int c = 0; c < 2; ++c) {
      int idx = c * 2048 + t * 8;
      int row = idx >> 5, col = idx & 31;
      g2l16(&A[(size_t)(bm + row) * K + k0 + col], &As[buf][c * 2048 + wave * 512]);
      g2l16(&Bt[(size_t)(bn + row) * K + k0 + col], &Bs[buf][c * 2048 + wave * 512]);
    }
  };

  auto compute = [&](int buf) {
    bf16x8v a[4], b[4];
#pragma unroll
    for (int mi = 0; mi < 4; ++mi)
      a[mi] = *(const bf16x8v*)&As[buf][(wm + mi * 16 + l16) * 32 + quad * 8];
#pragma unroll
    for (int ni = 0; ni < 4; ++ni)
      b[ni] = *(const bf16x8v*)&Bs[buf][(wn + ni * 16 + l16) * 32 + quad * 8];
#pragma unroll
    for (int mi = 0; mi < 4; ++mi)
#pragma unroll
      for (int ni = 0; ni < 4; ++ni)
        acc[mi][ni] = __builtin_amdgcn_mfma_f32_16x16x32_bf16(a[mi], b[ni],
                                                              acc[mi][ni], 0, 0, 0);
  };

  stage(0, 0);
  asm volatile("s_waitcnt vmcnt(0)" ::: "memory");
  __builtin_amdgcn_s_barrier();
  stage(1, 1);

  int bufc = 0;
  for (int tt = 0; tt < 30; ++tt) {
    int bufs = bufc + 2; if (bufs >= 3) bufs -= 3;
    stage(tt + 2, bufs);
    compute(bufc);
    asm volatile("s_waitcnt vmcnt(4)" ::: "memory");
    __builtin_amdgcn_s_barrier();
    bufc = (bufc == 2) ? 0 : bufc + 1;
  }
  compute(bufc);
  asm volatile("s_waitcnt vmcnt(0)" ::: "memory");
  __builtin_amdgcn_s_barrier();
  bufc = (bufc == 2) ? 0 : bufc + 1;
  compute(bufc);

  if (z == 2) {
    // V^T store: s = m&2047 contiguous along r -> pack 4 bf16 per 8B store
#pragma unroll
    for (int ni = 0; ni < 4; ++ni) {
      int n = bn + wn + ni * 16 + l16;
      float bz = bias[n];
      int h_ = n >> 6, d_ = n & 63;
#pragma unroll
      for (int mi = 0; mi < 4; ++mi) {
        int m0 = bm + wm + mi * 16 + quad * 4;
        int b_ = m0 >> 11, s0 = m0 & 2047;
        uint2 u;
        u.x = packbf(fclamp(acc[mi][ni][0] + bz), fclamp(acc[mi][ni][1] + bz));
        u.y = packbf(fclamp(acc[mi][ni][2] + bz), fclamp(acc[mi][ni][3] + bz));
        *(uint2*)&C[((size_t)(b_ * 16 + h_) * 64 + d_) * 2048 + s0] = u;
      }
    }
  } else {
    const float scl = (z == 0) ? QSCL : 1.0f;  // fold softmax scale into Q
#pragma unroll
    for (int ni = 0; ni < 4; ++ni) {
      int n = bn + wn + ni * 16 + l16;
      float bz = bias[n];
      int h_ = n >> 6, d_ = n & 63;
#pragma unroll
      for (int mi = 0; mi < 4; ++mi)
#pragma unroll
        for (int r = 0; r < 4; ++r) {
          int m = bm + wm + mi * 16 + quad * 4 + r;
          int b_ = m >> 11, s_ = m & 2047;
          C[((size_t)(b_ * 16 + h_) * 2048 + s_) * 64 + d_] =
              __float2bfloat16(fclamp(acc[mi][ni][r] + bz) * scl);
        }
    }
  }
}

// ---------------------------------------------------------------------------
// Output projection: 128x64 tile, triple-buffered 2-ahead pipeline.
// ---------------------------------------------------------------------------
__global__ __launch_bounds__(256, 2) void gemm_out(
    const bf16* __restrict__ A, const bf16* __restrict__ Bt,
    const float* __restrict__ bias, float* __restrict__ C) {
  constexpr int K = 1024, N = 1024;
  __shared__ alignas(16) bf16 As[3][128 * 32];
  __shared__ alignas(16) bf16 Bs[3][64 * 32];
  const int t = threadIdx.x;
  const int wave = t >> 6, lane = t & 63;
  const int quad = lane >> 4, l16 = lane & 15;
  const int bm = blockIdx.x * 128, bn = blockIdx.y * 64;
  const int wm = (wave & 1) * 64, wn = (wave >> 1) * 32;

  f32x4v acc[4][2] = {};

  auto stage = [&](int ks, int buf) {  // 3 g2l16/thread
    int k0 = ks * 32;
#pragma unroll
    for (int c = 0; c < 2; ++c) {
      int idx = c * 2048 + t * 8;
      int row = idx >> 5, col = idx & 31;
      g2l16(&A[(size_t)(bm + row) * K + k0 + col], &As[buf][c * 2048 + wave * 512]);
    }
    {
      int idx = t * 8;
      int row = idx >> 5, col = idx & 31;
      g2l16(&Bt[(size_t)(bn + row) * K + k0 + col], &Bs[buf][wave * 512]);
    }
  };

  auto compute = [&](int buf) {
    bf16x8v a[4], b[2];
#pragma unroll
    for (int mi = 0; mi < 4; ++mi)
      a[mi] = *(const bf16x8v*)&As[buf][(wm + mi * 16 + l16) * 32 + quad * 8];
#pragma unroll
    for (int ni = 0; ni < 2; ++ni)
      b[ni] = *(const bf16x8v*)&Bs[buf][(wn + ni * 16 + l16) * 32 + quad * 8];
#pragma unroll
    for (int mi = 0; mi < 4; ++mi)
#pragma unroll
      for (int ni = 0; ni < 2; ++ni)
        acc[mi][ni] = __builtin_amdgcn_mfma_f32_16x16x32_bf16(a[mi], b[ni],
                                                              acc[mi][ni], 0, 0, 0);
  };

  stage(0, 0);
  asm volatile("s_waitcnt vmcnt(0)" ::: "memory");
  __builtin_amdgcn_s_barrier();
  stage(1, 1);

  int bufc = 0;
  for (int tt = 0; tt < 30; ++tt) {
    int bufs = bufc + 2; if (bufs >= 3) bufs -= 3;
    stage(tt + 2, bufs);
    compute(bufc);
    asm volatile("s_waitcnt vmcnt(3)" ::: "memory");
    __builtin_amdgcn_s_barrier();
    bufc = (bufc == 2) ? 0 : bufc + 1;
  }
  compute(bufc);
  asm volatile("s_waitcnt vmcnt(0)" ::: "memory");
  __builtin_amdgcn_s_barrier();
  bufc = (bufc == 2) ? 0 : bufc + 1;
  compute(bufc);

#pragma unroll
  for (int ni = 0; ni < 2; ++ni) {
    int n = bn + wn + ni * 16 + l16;
    float bz = bias[n];
#pragma unroll
    for (int mi = 0; mi < 4; ++mi)
#pragma unroll
      for (int r = 0; r < 4; ++r) {
        int m = bm + wm + mi * 16 + quad * 4 + r;
        C[(size_t)m * N + n] = fclamp(acc[mi][ni][r] + bz);
      }
  }
}

// ---------------------------------------------------------------------------
// Flash attention v10: KVBLK=128 (16 tiles of 128 keys, 4 h-phases each).
// Halves barrier/vmcnt/chain-restart count vs v8 at identical staging bytes
// and fragment layouts: K/V tiles stored as TWO 64-wide sub-tiles (hc=h>>1)
// so g2l16's linear-dest constraint and the XOR chunk swizzle carry over.
// 2-buffer 1-ahead: stage(t+1) at phase top, vmcnt(0)+barrier after the
// ~1200-cy compute (covers the L2-resident ~300-cy stage latency; K/V is
// L2-local via the XCD-bijective decode, FETCH 12 MB). LDS 80 KB ->
// 2 blocks/CU, 16 waves/CU. Keeps: 512-thr blocks, swapped QK^T + packed
// b64 P-store, Qs/Ps union, Q-hoist, MFMA row-sum, setprio.
// ---------------------------------------------------------------------------
__global__ __launch_bounds__(512, 4) void attn(
    const bf16* __restrict__ Qh, const bf16* __restrict__ Kh,
    const bf16* __restrict__ Vt, bf16* __restrict__ Ctx) {
  constexpr int LDPP = 40;  // Ps row stride (16B-aligned rows: 80 B)
  __shared__ alignas(16) bf16 QsPs[128 * 64];   // Qs (prologue) / Ps (loop)
  __shared__ alignas(16) bf16 Ks[2][128 * 64];  // [buf][hc*4096 + r64*64 + c]
  __shared__ alignas(16) bf16 Vs[2][128 * 64];  // [buf][hc*4096 + d64*64 + k]
  const int t = threadIdx.x;
  const int wave = t >> 6, lane = t & 63;  // wave 0..7
  const int quad = lane >> 4, l16 = lane & 15;
  const int sw = l16 & 7;  // per-lane chunk swizzle key (row&7 == l16&7)

  // XCD-bijective decode: lin%8 = XCD; each XCD gets 4 bh x 16 qb.
  const int lin = blockIdx.x;       // 0..511
  const int li = lin >> 3;          // 0..63
  const int qb = li & 15;           // 0..15
  const int bh = (lin & 7) * 4 + (li >> 4);  // 0..31

  const size_t bh_off = (size_t)bh * 2048 * 64;
  const bf16* Qb = Qh + bh_off;
  const bf16* Kb = Kh + bh_off;
  const bf16* Vb = Vt + bh_off;  // [64][2048]

  // staging coords: 512 threads cover one 64x64 sub-tile per pass
  const int srow = t >> 3;   // 0..63
  const int schunk = t & 7;

  auto stageKV = [&](int kt, int buf) {  // kt = 128-key tile 0..15
    int mc = schunk ^ (srow & 7);
#pragma unroll
    for (int c = 0; c < 2; ++c) {  // key-half sub-tiles
      g2l16(&Kb[(size_t)(kt * 128 + c * 64 + srow) * 64 + mc * 8],
            &Ks[buf][c * 4096 + wave * 512]);
      g2l16(&Vb[(size_t)srow * 2048 + kt * 128 + c * 64 + mc * 8],
            &Vs[buf][c * 4096 + wave * 512]);
    }
  };

  // prologue: Q (2 loads) then tile 0 (4 loads); vmcnt(4) -> Q done.
#pragma unroll
  for (int c = 0; c < 2; ++c) {
    int row = c * 64 + srow;
    int mc = schunk ^ (row & 7);
    g2l16(&Qb[(size_t)(qb * 128 + row) * 64 + mc * 8],
          &QsPs[c * 4096 + wave * 512]);
  }
  stageKV(0, 0);
  asm volatile("s_waitcnt vmcnt(4)" ::: "memory");
  __builtin_amdgcn_s_barrier();

  // Q-hoist: fragments are kt-invariant, keep in registers (8 VGPR)
  bf16x8v aq[2];  // [kk]
#pragma unroll
  for (int kk = 0; kk < 2; ++kk)
    aq[kk] = *(const bf16x8v*)
        &QsPs[(wave * 16 + l16) * 64 + (((kk * 4 + quad) ^ sw) << 3)];

  // Qs region now dead -> reuse as Ps. __syncthreads drains vmcnt too,
  // so tile 0 is fully resident past this point.
  __syncthreads();
  bf16* Psw = QsPs + wave * (16 * LDPP);  // per-wave P buffer (1280 B)

  // all-ones B fragment for MFMA row-sum
  bf16x8v vone;
#pragma unroll
  for (int i = 0; i < 8; ++i) vone[i] = (__bf16)1.0f;

  f32x4v lsum = {};
  f32x4v oacc[4] = {};

  auto compute = [&](int buf) {
#pragma unroll
    for (int h = 0; h < 4; ++h) {  // four 32-key phases per 128-key tile
      const int hc = h >> 1, hl = h & 1;
      // S^T = K(32x64) x Q^T(64x16): row=key(quad*4+r), col=q(l16)
      f32x4v s[2] = {};  // [ni]
      __builtin_amdgcn_s_setprio(1);
#pragma unroll
      for (int kk = 0; kk < 2; ++kk)
#pragma unroll
        for (int ni = 0; ni < 2; ++ni) {
          bf16x8v bk = *(const bf16x8v*)
              &Ks[buf][hc * 4096 + (hl * 32 + ni * 16 + l16) * 64 +
                       (((kk * 4 + quad) ^ sw) << 3)];
          s[ni] = __builtin_amdgcn_mfma_f32_16x16x32_bf16(bk, aq[kk],
                                                          s[ni], 0, 0, 0);
        }
      __builtin_amdgcn_s_setprio(0);

      // P = exp2(S); 4 consecutive keys/lane -> pack -> one b64 write each.
#pragma unroll
      for (int ni = 0; ni < 2; ++ni) {
        float p0 = __builtin_amdgcn_exp2f(fminf(s[ni][0], 80.f));
        float p1 = __builtin_amdgcn_exp2f(fminf(s[ni][1], 80.f));
        float p2 = __builtin_amdgcn_exp2f(fminf(s[ni][2], 80.f));
        float p3 = __builtin_amdgcn_exp2f(fminf(s[ni][3], 80.f));
        uint2 u;
        u.x = packbf(p0, p1);
        u.y = packbf(p2, p3);
        *(uint2*)&Psw[l16 * LDPP + ni * 16 + quad * 4] = u;
      }

      // O += P(16x32) x V(32x64); l += P x ones (row-sum on matrix pipe)
      bf16x8v ap = *(const bf16x8v*)&Psw[l16 * LDPP + quad * 8];
      __builtin_amdgcn_s_setprio(1);
      lsum = __builtin_amdgcn_mfma_f32_16x16x32_bf16(ap, vone, lsum, 0, 0, 0);
#pragma unroll
      for (int ni = 0; ni < 4; ++ni) {
        bf16x8v bv = *(const bf16x8v*)
            &Vs[buf][hc * 4096 + (ni * 16 + l16) * 64 +
                     (((hl * 4 + quad) ^ sw) << 3)];
        oacc[ni] = __builtin_amdgcn_mfma_f32_16x16x32_bf16(ap, bv, oacc[ni],
                                                           0, 0, 0);
      }
      __builtin_amdgcn_s_setprio(0);
    }
  };

  // main loop: stage(t+1) at top -> compute(t) -> vmcnt(0)+barrier.
  // Buffer t+1's previous readers finished at barrier of t-1 -> race-free.
  for (int tt = 0; tt < 16; ++tt) {
    if (tt + 1 < 16) stageKV(tt + 1, (tt + 1) & 1);
    compute(tt & 1);
    if (tt + 1 < 16) {
      asm volatile("s_waitcnt vmcnt(0)" ::: "memory");
      __builtin_amdgcn_s_barrier();
    }
  }

  // epilogue: O / l -> Ctx[b][s][h*64+dh]
  const int b_ = bh >> 4, h_ = bh & 15;
#pragma unroll
  for (int r = 0; r < 4; ++r) {
    int sr = qb * 128 + wave * 16 + quad * 4 + r;
    float inv = 1.0f / fmaxf(lsum[r], 1.0e-20f);
#pragma unroll
    for (int ni = 0; ni < 4; ++ni) {
      int col = h_ * 64 + ni * 16 + l16;
      Ctx[(size_t)(b_ * 2048 + sr) * 1024 + col] =
          __float2bfloat16(fclamp(oacc[ni][r] * inv));
    }
  }
}

extern "C" void kernel_launch(void* const* d_in, const int* in_sizes, int n_in,
                              void* d_out, int out_size, void* d_ws, size_t ws_size,
                              hipStream_t stream) {
  const float* q   = (const float*)d_in[0];
  const float* k   = (const float*)d_in[1];
  const float* v   = (const float*)d_in[2];
  const float* w_q = (const float*)d_in[3];
  const float* b_q = (const float*)d_in[4];
  const float* w_k = (const float*)d_in[5];
  const float* b_k = (const float*)d_in[6];
  const float* w_v = (const float*)d_in[7];
  const float* b_v = (const float*)d_in[8];
  const float* w_o = (const float*)d_in[9];
  const float* b_o = (const float*)d_in[10];
  float* out = (float*)d_out;

  char* ws = (char*)d_ws;
  const size_t MB = (size_t)1024 * 1024;
  bf16* WtQ = (bf16*)(ws + 0 * MB);
  bf16* WtK = (bf16*)(ws + 2 * MB);
  bf16* WtV = (bf16*)(ws + 4 * MB);
  bf16* WtO = (bf16*)(ws + 6 * MB);
  bf16* Qa  = (bf16*)(ws + 8 * MB);   // bf16 activations (8 MiB each)
  bf16* Ka  = (bf16*)(ws + 16 * MB);
  bf16* Va  = (bf16*)(ws + 24 * MB);
  bf16* Qh  = (bf16*)(ws + 32 * MB);  // [2,16,2048,64]
  bf16* Kh  = (bf16*)(ws + 40 * MB);
  bf16* Vt  = (bf16*)(ws + 48 * MB);  // [2,16,64,2048]
  bf16* Ctx = Qa;                     // Qa dead after gemm_qkv

  dim3 tb(256);
  prep<<<dim3(7168), tb, 0, stream>>>(q, k, v, w_q, w_k, w_v, w_o,
                                      Qa, Ka, Va, WtQ, WtK, WtV, WtO);
  gemm_qkv_bf16<<<dim3(32, 8, 3), tb, 0, stream>>>(Qa, Ka, Va, WtQ, WtK, WtV,
                                                   b_q, b_k, b_v, Qh, Kh, Vt);
  attn<<<dim3(512), dim3(512), 0, stream>>>(Qh, Kh, Vt, Ctx);
  gemm_out<<<dim3(32, 16), tb, 0, stream>>>(Ctx, WtO, b_o, out);
}